// Round 8
// baseline (282.719 us; speedup 1.0000x reference)
//
#include <hip/hip_runtime.h>

// Problem constants: B=4, L=1024, D=512, N=16, OUT=512, NL=2
#define BQ 4
#define LQ 1024
#define DQ 512
#define NQ 16
#define MQ (BQ*LQ)      // 4096 rows (b,l flattened)
#define CHUNK 32
#define NCH (LQ/CHUNK)  // 32 chunks
#define KQ 512
#define NFUSE 576       // 512 dt + 16 B + 16 C + 32 pad

typedef __bf16  bf16x8  __attribute__((ext_vector_type(8)));
typedef float   floatx4 __attribute__((ext_vector_type(4)));

__device__ __forceinline__ float softplus_f(float x) {
    return (x > 20.0f) ? x : log1pf(__expf(x));
}
__device__ __forceinline__ unsigned short f2b(float f) {
    union { float f; unsigned u; } x; x.f = f;
    unsigned r = x.u + 0x7fffu + ((x.u >> 16) & 1u);
    return (unsigned short)(r >> 16);
}
__device__ __forceinline__ float b2f(unsigned short u) {
    union { unsigned u; float f; } x; x.u = (unsigned)u << 16;
    return x.f;
}

// ===========================================================================
// Flat wave-GEMM: 32x32 tile PER WAVE, fragments loaded directly global->VGPR
// (16 contiguous bytes/lane = exact mfma_16x16x32_bf16 operand). No LDS, no
// barriers, no vmcnt(0) drains. 256-thr blocks = 4 waves sharing one B-tile
// (L1 reuse); job = (mGroup*4+wave, nIdx). Occupancy 9 waves/CU (fused) with
// ~16 loads in flight per wave (unroll 4) hides L2 latency.
// r4's version of this failed ONLY because 64-thr blocks left 2.25 waves/CU.
// ===========================================================================
__device__ __forceinline__ void gemm_fw_core(
    const unsigned short* __restrict__ Abf,
    const unsigned short* __restrict__ Wt,
    int bm, int bn, int lane, floatx4 acc[2][2])
{
    const int r15 = lane & 15, q = lane >> 4;
    const unsigned short* ap = Abf + (size_t)(bm + r15) * KQ + q * 8;
    const unsigned short* bp = Wt  + (size_t)(bn + r15) * KQ + q * 8;
    #pragma unroll
    for (int i = 0; i < 2; ++i)
        #pragma unroll
        for (int j = 0; j < 2; ++j) acc[i][j] = (floatx4){0.f,0.f,0.f,0.f};
    #pragma unroll 4
    for (int k0 = 0; k0 < KQ; k0 += 32) {
        bf16x8 a0 = *(const bf16x8*)(ap + k0);
        bf16x8 a1 = *(const bf16x8*)(ap + 16 * KQ + k0);
        bf16x8 b0 = *(const bf16x8*)(bp + k0);
        bf16x8 b1 = *(const bf16x8*)(bp + 16 * KQ + k0);
        acc[0][0] = __builtin_amdgcn_mfma_f32_16x16x32_bf16(a0, b0, acc[0][0], 0,0,0);
        acc[1][0] = __builtin_amdgcn_mfma_f32_16x16x32_bf16(a1, b0, acc[1][0], 0,0,0);
        acc[0][1] = __builtin_amdgcn_mfma_f32_16x16x32_bf16(a0, b1, acc[0][1], 0,0,0);
        acc[1][1] = __builtin_amdgcn_mfma_f32_16x16x32_bf16(a1, b1, acc[1][1], 0,0,0);
    }
}

// ---------------------------------------------------------------------------
// Plain: out = A@Wt^T + bias. Jobs: (M/32) m-tiles x ntn n-tiles.
// grid = (M/32/4) * ntn blocks; block's 4 waves share one n-tile.
// ---------------------------------------------------------------------------
template<bool F32OUT>
__global__ __launch_bounds__(256) void gemm_fw(
    const unsigned short* __restrict__ Abf,
    const unsigned short* __restrict__ Wt,
    const float* __restrict__ bias,
    float* __restrict__ Cf, unsigned short* __restrict__ Cb,
    int N, int ntn)
{
    const int lane = threadIdx.x & 63, wave = threadIdx.x >> 6;
    const int nIdx = blockIdx.x % ntn, mGrp = blockIdx.x / ntn;
    const int bm = (mGrp * 4 + wave) * 32, bn = nIdx * 32;
    floatx4 acc[2][2];
    gemm_fw_core(Abf, Wt, bm, bn, lane, acc);

    const int col0 = lane & 15, rq = lane >> 4;
    #pragma unroll
    for (int nt = 0; nt < 2; ++nt) {
        int n = bn + nt * 16 + col0;
        float bv = bias[n];
        #pragma unroll
        for (int mt = 0; mt < 2; ++mt)
            #pragma unroll
            for (int r = 0; r < 4; ++r) {
                int m = bm + mt * 16 + rq * 4 + r;
                float v = acc[mt][nt][r] + bv;
                if (F32OUT) Cf[(size_t)m * N + n] = v;
                else        Cb[(size_t)m * N + n] = f2b(v);
            }
    }
}

// ---------------------------------------------------------------------------
// Fused dt/B/C: Wt rows 0-511 Wdt^T, 512-527 WB^T, 528-543 WC^T, 544-575 zero.
// ntn = 18. dt written bf16 with softplus fused.
// ---------------------------------------------------------------------------
__global__ __launch_bounds__(256) void gemm_fw_fused(
    const unsigned short* __restrict__ Abf,
    const unsigned short* __restrict__ Wt,
    const float* __restrict__ bdt, const float* __restrict__ bB,
    const float* __restrict__ bC,
    unsigned short* __restrict__ dtb, float* __restrict__ Bm, float* __restrict__ Cm)
{
    const int lane = threadIdx.x & 63, wave = threadIdx.x >> 6;
    const int nIdx = blockIdx.x % 18, mGrp = blockIdx.x / 18;
    const int bm = (mGrp * 4 + wave) * 32, bn = nIdx * 32;
    floatx4 acc[2][2];
    gemm_fw_core(Abf, Wt, bm, bn, lane, acc);

    const int col0 = lane & 15, rq = lane >> 4;
    #pragma unroll
    for (int nt = 0; nt < 2; ++nt) {
        int nb = bn + nt * 16;      // 16-col region selector (frag-uniform)
        int n  = nb + col0;
        if (nb < 512) {
            float bv = bdt[n];
            #pragma unroll
            for (int mt = 0; mt < 2; ++mt)
                #pragma unroll
                for (int r = 0; r < 4; ++r) {
                    int m = bm + mt * 16 + rq * 4 + r;
                    dtb[(size_t)m * DQ + n] = f2b(softplus_f(acc[mt][nt][r] + bv));
                }
        } else if (nb < 528) {
            float bv = bB[n - 512];
            #pragma unroll
            for (int mt = 0; mt < 2; ++mt)
                #pragma unroll
                for (int r = 0; r < 4; ++r) {
                    int m = bm + mt * 16 + rq * 4 + r;
                    Bm[(size_t)m * NQ + (n - 512)] = acc[mt][nt][r] + bv;
                }
        } else if (nb < 544) {
            float bv = bC[n - 528];
            #pragma unroll
            for (int mt = 0; mt < 2; ++mt)
                #pragma unroll
                for (int r = 0; r < 4; ++r) {
                    int m = bm + mt * 16 + rq * 4 + r;
                    Cm[(size_t)m * NQ + (n - 528)] = acc[mt][nt][r] + bv;
                }
        }
        // nb >= 544: zero pad, skip
    }
}

// ---------------------------------------------------------------------------
// ALL prep in ONE dispatch, branch on blockIdx:
//   [0,1280):   weight transpose+cast (5 mats x 256 tiles of 32x32)
//   [1280,1408): pack WB/WC into Wf rows 512..575
//   [1408,3456): cast x -> bf16 (1024 elems/block)
// ---------------------------------------------------------------------------
__global__ __launch_bounds__(256) void prep_all(
    const float* __restrict__ Wdt, const float* __restrict__ Wlin,
    const float* __restrict__ Wdec,
    const float* __restrict__ WB, const float* __restrict__ WC,
    const float* __restrict__ x,
    unsigned short* __restrict__ Wf, unsigned short* __restrict__ Wt_lin,
    unsigned short* __restrict__ Wt_dec, unsigned short* __restrict__ y16)
{
    const int bid = blockIdx.x, tid = threadIdx.x;
    if (bid < 1280) {
        __shared__ float tile[32][33];
        int mat = bid >> 8, t = bid & 255;
        const float* src; unsigned short* dst;
        switch (mat) {
            case 0:  src = Wdt;                  dst = Wf;                    break;
            case 1:  src = Wdt + (size_t)KQ*KQ;  dst = Wf + (size_t)NFUSE*KQ; break;
            case 2:  src = Wlin;                 dst = Wt_lin;                break;
            case 3:  src = Wlin + (size_t)KQ*KQ; dst = Wt_lin + (size_t)KQ*KQ;break;
            default: src = Wdec;                 dst = Wt_dec;                break;
        }
        int bx = (t & 15) * 32, by = (t >> 4) * 32;
        int tx = tid & 31, ty = tid >> 5;       // 32 x 8
        #pragma unroll
        for (int i = 0; i < 32; i += 8)
            tile[ty + i][tx] = src[(size_t)(bx + ty + i) * KQ + by + tx];
        __syncthreads();
        #pragma unroll
        for (int i = 0; i < 32; i += 8)
            dst[(size_t)(by + ty + i) * KQ + bx + tx] = f2b(tile[tx][ty + i]);
    } else if (bid < 1408) {
        int job = bid - 1280;
        int layer = job >> 6, r = job & 63;
        unsigned short* dst = Wf + (size_t)layer * NFUSE * KQ + (size_t)(512 + r) * KQ;
        const float* src = nullptr;
        int n = 0;
        if (r < 16)      { src = WB + (size_t)layer * DQ * NQ; n = r; }
        else if (r < 32) { src = WC + (size_t)layer * DQ * NQ; n = r - 16; }
        for (int k = tid; k < KQ; k += 256)
            dst[k] = src ? f2b(src[(size_t)k * NQ + n]) : (unsigned short)0;
    } else {
        size_t i = ((size_t)(bid - 1408) * 256 + tid) * 4;
        float4 v = *(const float4*)(x + i);
        ushort4 o;
        o.x = f2b(v.x); o.y = f2b(v.y); o.z = f2b(v.z); o.w = f2b(v.w);
        *(ushort4*)(y16 + i) = o;
    }
}

// ---------------------------------------------------------------------------
// Scan phase 1: per (b,d,chunk) cumulative a-product + local h (zero-init).
// ---------------------------------------------------------------------------
__global__ __launch_bounds__(256) void scan_phase1(
    const unsigned short* __restrict__ dt, const unsigned short* __restrict__ y,
    const float* __restrict__ Bm, const float* __restrict__ A,
    float* __restrict__ ap, float* __restrict__ hf)
{
    int idx  = blockIdx.x;
    int dblk = idx & 1;
    int c    = (idx >> 1) & (NCH - 1);
    int b    = idx >> 6;
    int d    = dblk * 256 + threadIdx.x;

    float Ad[NQ];
    const float* Aptr = A + (size_t)d * NQ;
    #pragma unroll
    for (int n = 0; n < NQ; ++n) Ad[n] = Aptr[n];

    float h[NQ], prod[NQ];
    #pragma unroll
    for (int n = 0; n < NQ; ++n) { h[n] = 0.f; prod[n] = 1.f; }

    int t0 = c * CHUNK;
    const unsigned short* dtp = dt + ((size_t)b*LQ + t0) * DQ + d;
    const unsigned short* yp  = y  + ((size_t)b*LQ + t0) * DQ + d;
    const float* bp  = Bm + ((size_t)b*LQ + t0) * NQ;

    #pragma unroll 4
    for (int t = 0; t < CHUNK; ++t) {
        float dtv = b2f(dtp[(size_t)t * DQ]);
        float yv  = b2f(yp[(size_t)t * DQ]);
        float dty = dtv * yv;
        #pragma unroll
        for (int n = 0; n < NQ; ++n) {
            float a = __expf(dtv * Ad[n]);
            prod[n] *= a;
            h[n] = fmaf(a, h[n], dty * bp[t*NQ + n]);
        }
    }
    size_t base = ((size_t)(b*NCH + c) * DQ + d) * NQ;
    #pragma unroll
    for (int n = 0; n < NQ; n += 4) {
        *(float4*)(ap + base + n) = make_float4(prod[n], prod[n+1], prod[n+2], prod[n+3]);
        *(float4*)(hf + base + n) = make_float4(h[n], h[n+1], h[n+2], h[n+3]);
    }
}

// ---------------------------------------------------------------------------
// Scan phase 2: scan over NCH chunk summaries; h_init in-place over ap.
// Loads batched in groups of 8 -> 4 latency rounds.
// ---------------------------------------------------------------------------
__global__ __launch_bounds__(256) void scan_phase2(
    float* ap, const float* __restrict__ hf)
{
    int g = blockIdx.x * 256 + threadIdx.x;   // B*D*N threads
    int n = g & (NQ - 1);
    int d = (g >> 4) & (DQ - 1);
    int b = g >> 13;
    const size_t stride = (size_t)DQ * NQ;
    size_t base = ((size_t)b * NCH * DQ + d) * NQ + n;
    float h = 0.f;
    for (int c0 = 0; c0 < NCH; c0 += 8) {
        float a[8], f[8];
        #pragma unroll
        for (int j = 0; j < 8; ++j) {
            size_t idx = base + (size_t)(c0 + j) * stride;
            a[j] = ap[idx];
            f[j] = hf[idx];
        }
        #pragma unroll
        for (int j = 0; j < 8; ++j) {
            size_t idx = base + (size_t)(c0 + j) * stride;
            ap[idx] = h;
            h = fmaf(a[j], h, f[j]);
        }
    }
}

// ---------------------------------------------------------------------------
// Scan phase 3: recompute local scan with h_init, emit bf16
// yact = relu(sum_n h*Cm + Dskip*y)
// ---------------------------------------------------------------------------
__global__ __launch_bounds__(256) void scan_phase3(
    const unsigned short* __restrict__ dt, const unsigned short* __restrict__ y,
    const float* __restrict__ Bm, const float* __restrict__ Cm,
    const float* __restrict__ A, const float* __restrict__ Dsk,
    const float* __restrict__ hi, unsigned short* __restrict__ yact)
{
    int idx  = blockIdx.x;
    int dblk = idx & 1;
    int c    = (idx >> 1) & (NCH - 1);
    int b    = idx >> 6;
    int d    = dblk * 256 + threadIdx.x;

    float Ad[NQ];
    const float* Aptr = A + (size_t)d * NQ;
    #pragma unroll
    for (int n = 0; n < NQ; ++n) Ad[n] = Aptr[n];

    float h[NQ];
    size_t base = ((size_t)(b*NCH + c) * DQ + d) * NQ;
    #pragma unroll
    for (int n = 0; n < NQ; n += 4) {
        float4 v = *(const float4*)(hi + base + n);
        h[n] = v.x; h[n+1] = v.y; h[n+2] = v.z; h[n+3] = v.w;
    }
    float dskip = Dsk[d];

    int t0 = c * CHUNK;
    const unsigned short* dtp = dt + ((size_t)b*LQ + t0) * DQ + d;
    const unsigned short* yp  = y  + ((size_t)b*LQ + t0) * DQ + d;
    const float* bp  = Bm + ((size_t)b*LQ + t0) * NQ;
    const float* cp  = Cm + ((size_t)b*LQ + t0) * NQ;
    unsigned short* op = yact + ((size_t)b*LQ + t0) * DQ + d;

    #pragma unroll 4
    for (int t = 0; t < CHUNK; ++t) {
        float dtv = b2f(dtp[(size_t)t * DQ]);
        float yv  = b2f(yp[(size_t)t * DQ]);
        float dty = dtv * yv;
        float acc = 0.f;
        #pragma unroll
        for (int n = 0; n < NQ; ++n) {
            float a = __expf(dtv * Ad[n]);
            h[n] = fmaf(a, h[n], dty * bp[t*NQ + n]);
            acc = fmaf(h[n], cp[t*NQ + n], acc);
        }
        float v = acc + dskip * yv;
        op[(size_t)t * DQ] = f2b(fmaxf(v, 0.f));
    }
}

// ---------------------------------------------------------------------------
extern "C" void kernel_launch(void* const* d_in, const int* in_sizes, int n_in,
                              void* d_out, int out_size, void* d_ws, size_t ws_size,
                              hipStream_t stream)
{
    const float* x    = (const float*)d_in[0];
    const float* A    = (const float*)d_in[1];
    const float* Dsk  = (const float*)d_in[2];
    const float* WB   = (const float*)d_in[3];
    const float* bB   = (const float*)d_in[4];
    const float* WC   = (const float*)d_in[5];
    const float* bC   = (const float*)d_in[6];
    const float* Wdt  = (const float*)d_in[7];
    const float* bdt  = (const float*)d_in[8];
    const float* Wlin = (const float*)d_in[9];
    const float* blin = (const float*)d_in[10];
    const float* Wdec = (const float*)d_in[11];
    const float* bdec = (const float*)d_in[12];
    float* out = (float*)d_out;

    // workspace layout
    char* cur = (char*)d_ws;
    float* Bm   = (float*)cur;           cur += (size_t)MQ*NQ*4;          // 256 KB
    float* Cm   = (float*)cur;           cur += (size_t)MQ*NQ*4;          // 256 KB
    float* ap   = (float*)cur;           cur += (size_t)BQ*NCH*DQ*NQ*4;   // 4 MB
    float* hf   = (float*)cur;           cur += (size_t)BQ*NCH*DQ*NQ*4;   // 4 MB
    unsigned short* y16    = (unsigned short*)cur; cur += (size_t)MQ*DQ*2;   // 4 MB
    unsigned short* dtb16  = (unsigned short*)cur; cur += (size_t)MQ*DQ*2;   // 4 MB
    unsigned short* yact16 = (unsigned short*)cur; cur += (size_t)MQ*DQ*2;   // 4 MB
    unsigned short* Wf     = (unsigned short*)cur; cur += (size_t)2*NFUSE*KQ*2; // 1.125 MB
    unsigned short* Wt_lin = (unsigned short*)cur; cur += (size_t)2*KQ*KQ*2;   // 1 MB
    unsigned short* Wt_dec = (unsigned short*)cur; cur += (size_t)KQ*KQ*2;     // 0.5 MB

    dim3 blk(256);

    // single prep dispatch (weights transposed+cast, B/C packed, x cast)
    prep_all<<<dim3(3456), blk, 0, stream>>>(
        Wdt, Wlin, Wdec, WB, WC, x, Wf, Wt_lin, Wt_dec, y16);

    for (int layer = 0; layer < 2; ++layer) {
        // dt (softplus, ->bf16) + Bm + Cm: flat wave-GEMM, 2304 wave-jobs
        gemm_fw_fused<<<dim3(32 * 18), blk, 0, stream>>>(
            y16, Wf + (size_t)layer*NFUSE*KQ,
            bdt + (size_t)layer*DQ, bB + (size_t)layer*NQ, bC + (size_t)layer*NQ,
            dtb16, Bm, Cm);
        // chunked scan (bf16 activations)
        scan_phase1<<<dim3(BQ*NCH*(DQ/256)), blk, 0, stream>>>(
            dtb16, y16, Bm, A + (size_t)layer*DQ*NQ, ap, hf);
        scan_phase2<<<dim3(BQ*DQ*NQ/256), blk, 0, stream>>>(ap, hf);
        scan_phase3<<<dim3(BQ*NCH*(DQ/256)), blk, 0, stream>>>(
            dtb16, y16, Bm, Cm, A + (size_t)layer*DQ*NQ, Dsk + (size_t)layer*DQ,
            ap, yact16);
        // y = yact @ Wlin + blin (bf16 out, overwrites y16): 2048 wave-jobs
        gemm_fw<false><<<dim3(32 * 16), blk, 0, stream>>>(
            yact16, Wt_lin + (size_t)layer*KQ*KQ, blin + (size_t)layer*DQ,
            (float*)nullptr, y16, DQ, 16);
    }
    // decoder (fp32 out)
    gemm_fw<true><<<dim3(32 * 16), blk, 0, stream>>>(
        y16, Wt_dec, bdec, out, (unsigned short*)nullptr, DQ, 16);
}